// Round 6
// baseline (219.623 us; speedup 1.0000x reference)
//
#include <hip/hip_runtime.h>
#include <math.h>

#define BATCH 64
#define CD 256
#define NX 784
#define TRIU_N 32896
#define MSZ 65536           // elems per swizzled 256x256 matrix
#define REG_STRIDE 1032     // A: 128 rows * 8 + 8 pad
#define A_ARR 4128          // A array stride (4 rid * 1032)
#define B_BASE 8256         // B region base (2 A arrays)
#define B_REG 520           // B: 64 rows * 8 + 8 pad
#define B_ARR 2080          // B array stride (4 rid * 520)
#define STG 12416           // full stage stride in ushorts (2*4128 + 2*2080)

typedef unsigned short ushort_t;
typedef unsigned int uint_t;
typedef __attribute__((ext_vector_type(8))) short short8;
typedef __attribute__((ext_vector_type(16))) float floatx16;

// XCD co-location, 512 blocks: bid = xcd + 8*(tile + 8*bbHigh).
// All 8 tiles of a batch land on one XCD (64 blocks/XCD = 2/CU).
__device__ __forceinline__ void decode_bid(int bid, int& tile, int& bb) {
    int xcd = bid & 7, g = bid >> 3;
    tile = g & 7;
    bb = ((g >> 3) << 3) | xcd;
}

__device__ __forceinline__ float bf2f(ushort_t h) {
    return __uint_as_float(((uint_t)h) << 16);
}
__device__ __forceinline__ void pack2(float f0, float f1, uint_t& hp, uint_t& lp) {
    uint_t h, l;
    asm("v_cvt_pk_bf16_f32 %0, %1, %2" : "=v"(h) : "v"(f0), "v"(f1));
    float r0 = f0 - __uint_as_float(h << 16);
    float r1 = f1 - __uint_as_float(h & 0xffff0000u);
    asm("v_cvt_pk_bf16_f32 %0, %1, %2" : "=v"(l) : "v"(r0), "v"(r1));
    hp = h; lp = l;
}
__device__ __forceinline__ void store8(ushort_t* H, ushort_t* L, const float* y) {
    uint_t hw[4], lw[4];
    #pragma unroll
    for (int i = 0; i < 4; ++i) pack2(y[2*i], y[2*i+1], hw[i], lw[i]);
    *(uint4*)H = make_uint4(hw[0], hw[1], hw[2], hw[3]);
    *(uint4*)L = make_uint4(lw[0], lw[1], lw[2], lw[3]);
}

// swizzled offset of element (r,c) within one 256x256 matrix
__device__ __forceinline__ int swoff(int r, int c) {
    int p = r >> 7, s = (c >> 5) & 7, ks = (c >> 4) & 1, kh = (c >> 3) & 1;
    return ((((p * 8 + s) * 2 + ks) * 2 + kh) * 128 + (r & 127)) * 8 + (c & 7);
}

// raw workgroup barrier (no compiler vmcnt(0) drain)
__device__ __forceinline__ void rawbar() {
    __builtin_amdgcn_s_barrier();
    __builtin_amdgcn_sched_barrier(0);
}

// ---------------------------------------------------------------------------
// One BK=32 stage, 128x64 tile, 4 waves: wave wv owns rows wv*32..+31 and
// both 32-col quadrants. 12 ds_read_b128 + 12 MFMA per wave per stage.
__device__ __forceinline__ void mfma_stage4(const ushort_t* us, int bufbase,
                                            int wv, int khalf, int lrow,
                                            floatx16* acc) {
    __builtin_amdgcn_s_setprio(1);
    #pragma unroll
    for (int ks = 0; ks < 2; ++ks) {
        const int rid = ks * 2 + khalf;
        const ushort_t* ra = us + bufbase + rid * REG_STRIDE + wv * 256 + lrow * 8;
        short8 aH = *(const short8*)(ra);
        short8 aL = *(const short8*)(ra + A_ARR);
        const ushort_t* rb = us + bufbase + B_BASE + rid * B_REG + lrow * 8;
        #pragma unroll
        for (int cq = 0; cq < 2; ++cq) {
            short8 bH = *(const short8*)(rb + cq * 256);
            short8 bL = *(const short8*)(rb + B_ARR + cq * 256);
            acc[cq] = __builtin_amdgcn_mfma_f32_32x32x16_bf16(aH, bH, acc[cq], 0, 0, 0);
            acc[cq] = __builtin_amdgcn_mfma_f32_32x32x16_bf16(aH, bL, acc[cq], 0, 0, 0);
            acc[cq] = __builtin_amdgcn_mfma_f32_32x32x16_bf16(aL, bH, acc[cq], 0, 0, 0);
        }
    }
    __builtin_amdgcn_s_setprio(0);
}

// accumulator -> fsmem bounce, 128x64 tile, stride 65 (conflict-free)
__device__ __forceinline__ void acc_bounce(float* fsmem, const floatx16* acc,
                                           int wv, int khalf, int lrow) {
    __syncthreads();
    #pragma unroll
    for (int cq = 0; cq < 2; ++cq)
        #pragma unroll
        for (int i = 0; i < 16; ++i) {
            int rl = (i & 3) + ((i >> 2) << 3) + (khalf << 2);
            fsmem[(wv * 32 + rl) * 65 + cq * 32 + lrow] = acc[cq][i];
        }
    __syncthreads();
}

// ---------------------------------------------------------------------------
// Gram staging: 3 slots/thread (A rows 0..63, A rows 64..127, B rows 0..63),
// kq = tid&3 picks the 8-float k-chunk. Named double buffer (rule #20).
struct Cur { float4 v[3][2]; };

__device__ __forceinline__ void gr_load(const float* Xb, int rowBase, int colBase, int s,
                                        int tid, Cur& c) {
    const int kq = tid & 3, rr = tid >> 2;
    const int xrow[3] = {rowBase + rr, rowBase + 64 + rr, colBase + rr};
    int gk = s * 32 + kq * 8;
    #pragma unroll
    for (int q = 0; q < 3; ++q) {
        if (gk < NX) {
            const float* p = Xb + (size_t)xrow[q] * NX + gk;
            c.v[q][0] = *(const float4*)p;
            c.v[q][1] = *(const float4*)(p + 4);
        } else {
            c.v[q][0] = make_float4(0.f, 0.f, 0.f, 0.f);
            c.v[q][1] = make_float4(0.f, 0.f, 0.f, 0.f);
        }
    }
}

__device__ __forceinline__ void gr_conv(ushort_t* us, int bufbase, const Cur& c,
                                        int tid, float* rs) {
    const int kq = tid & 3, rr = tid >> 2;
    const int lbase[3] = {kq * REG_STRIDE + rr * 8,
                          kq * REG_STRIDE + 512 + rr * 8,
                          B_BASE + kq * B_REG + rr * 8};
    const int lostep[3] = {A_ARR, A_ARR, B_ARR};
    #pragma unroll
    for (int q = 0; q < 3; ++q) {
        float f[8] = {c.v[q][0].x, c.v[q][0].y, c.v[q][0].z, c.v[q][0].w,
                      c.v[q][1].x, c.v[q][1].y, c.v[q][1].z, c.v[q][1].w};
        rs[q] += ((f[0] + f[1]) + (f[2] + f[3])) + ((f[4] + f[5]) + (f[6] + f[7]));
        uint_t hp[4], lp[4];
        #pragma unroll
        for (int i = 0; i < 4; ++i) pack2(f[2*i], f[2*i+1], hp[i], lp[i]);
        int base = bufbase + lbase[q];
        *(uint4*)(us + base)             = make_uint4(hp[0], hp[1], hp[2], hp[3]);
        *(uint4*)(us + base + lostep[q]) = make_uint4(lp[0], lp[1], lp[2], lp[3]);
    }
}

// ---------------------------------------------------------------------------
// Gram: Sigma = X X^T / n - m m^T. Means + trace fused. 128x64 tiles,
// 2 blocks/CU, 2-stage-ahead load pipeline, raw barriers + lgkmcnt(0).
__global__ __launch_bounds__(256, 2)
void gram_mfma(const float* __restrict__ X, float* __restrict__ means,
               float* __restrict__ tr,
               ushort_t* __restrict__ Gh, ushort_t* __restrict__ Gl) {
    __shared__ __align__(16) float fsmem[12416];   // 49.7 KB: 2 staging bufs / bounce overlay
    __shared__ float dsh[4];
    ushort_t* us = (ushort_t*)fsmem;
    int tile, bb;
    decode_bid(blockIdx.x, tile, bb);
    const int rowBase = (tile >> 2) * 128, colBase = (tile & 3) * 64;
    const int tid = threadIdx.x, lane = tid & 63, wv = tid >> 6;
    const int khalf = lane >> 5, lrow = lane & 31;
    const float* Xb = X + (size_t)bb * CD * NX;

    floatx16 acc[2];
    #pragma unroll
    for (int cq = 0; cq < 2; ++cq)
        #pragma unroll
        for (int i = 0; i < 16; ++i) acc[cq][i] = 0.f;

    float rs[3] = {0.f, 0.f, 0.f};
    Cur curA, curB;
    gr_load(Xb, rowBase, colBase, 0, tid, curA);
    gr_load(Xb, rowBase, colBase, 1, tid, curB);
    gr_conv(us, 0, curA, tid, rs);                  // stage 0 -> buf0

    for (int s = 0; s < 25; s += 2) {
        // ---- even stage s (reads buf0) ----
        asm volatile("s_waitcnt lgkmcnt(0)" ::: "memory");
        rawbar();
        if (s + 2 <= 24) gr_load(Xb, rowBase, colBase, s + 2, tid, curA);
        mfma_stage4(us, 0, wv, khalf, lrow, acc);
        if (s + 1 <= 24) gr_conv(us, STG, curB, tid, rs);
        // ---- odd stage s+1 (reads buf1) ----
        if (s + 1 <= 24) {
            asm volatile("s_waitcnt lgkmcnt(0)" ::: "memory");
            rawbar();
            if (s + 3 <= 24) gr_load(Xb, rowBase, colBase, s + 3, tid, curB);
            mfma_stage4(us, STG, wv, khalf, lrow, acc);
            gr_conv(us, 0, curA, tid, rs);
        }
    }

    // means: reduce over the 4 kq lanes sharing a row; write all 3 panels.
    {
        float r0 = rs[0], r1 = rs[1], r2 = rs[2];
        r0 += __shfl_xor(r0, 1, 64); r0 += __shfl_xor(r0, 2, 64);
        r1 += __shfl_xor(r1, 1, 64); r1 += __shfl_xor(r1, 2, 64);
        r2 += __shfl_xor(r2, 1, 64); r2 += __shfl_xor(r2, 2, 64);
        if ((tid & 3) == 0) {
            int rr = tid >> 2;                       // 0..63
            means[bb * CD + rowBase + rr]      = r0 * (1.0f / NX);
            means[bb * CD + rowBase + 64 + rr] = r1 * (1.0f / NX);
            means[bb * CD + colBase + rr]      = r2 * (1.0f / NX);
        }
    }

    acc_bounce(fsmem, acc, wv, khalf, lrow);   // full-drain syncthreads flushes means stores
    const int rloc = tid & 127;
    const int r = rowBase + rloc;
    const float mr = means[bb * CD + r];
    const bool diagblk = ((colBase >> 7) == (rowBase >> 7));
    float dv = 0.f;
    #pragma unroll
    for (int gi = 0; gi < 4; ++gi) {
        int g = (tid >> 7) + gi * 2;               // 0..7 col-groups of 8
        int c0 = colBase + g * 8;
        int so = swoff(r, c0);
        float v[8];
        #pragma unroll
        for (int j = 0; j < 8; ++j) {
            v[j] = fsmem[rloc * 65 + g * 8 + j] * (1.0f / NX) - mr * means[bb * CD + c0 + j];
            if (diagblk && (c0 + j) == r) dv += v[j];
        }
        store8(Gh + (size_t)bb * MSZ + so, Gl + (size_t)bb * MSZ + so, v);
    }
    if (diagblk) {
        for (int off = 32; off; off >>= 1) dv += __shfl_down(dv, off, 64);
        if (lane == 0) dsh[wv] = dv;
        __syncthreads();
        if (tid == 0)
            atomicAdd(&tr[bb], (dsh[0] + dsh[1]) + (dsh[2] + dsh[3]));
    }
}

// ---------------------------------------------------------------------------
// NS staging: 24 chunks/stage (A: 2 arrays x 4 rid x 2 halves; B: 2 x 4),
// 6 per wave, via global_load_lds (LDS dst wave-uniform, 64 lanes x 16 B).
__device__ __forceinline__ void ns_prefetch(const ushort_t* const* arrp, int bhalf,
                                            ushort_t* us, int wv, int lane,
                                            int s, int buf) {
    #pragma unroll
    for (int j = 0; j < 6; ++j) {
        int ck = wv * 6 + j;
        const ushort_t* g;
        ushort_t* l;
        if (ck < 16) {
            int arr = ck >> 3, rid = (ck >> 1) & 3, half = ck & 1;
            g = arrp[arr] + s * 4096 + rid * 1024 + half * 512 + lane * 8;
            l = us + buf + arr * A_ARR + rid * REG_STRIDE + half * 512;
        } else {
            int ck2 = ck - 16;
            int arr = ck2 >> 2, rid = ck2 & 3;
            g = arrp[2 + arr] + s * 4096 + rid * 1024 + bhalf * 512 + lane * 8;
            l = us + buf + B_BASE + arr * B_ARR + rid * B_REG;
        }
        __builtin_amdgcn_global_load_lds(
            (const __attribute__((address_space(1))) unsigned int*)g,
            (__attribute__((address_space(3))) unsigned int*)l, 16, 0, 0);
    }
}

// NS GEMM, 128x64 tiles, 2 blocks/CU, 3-buffer 1-barrier pipeline with
// counted vmcnt(6). 6-GEMM commutativity-restructured chain:
// MODE 2: y = 1.5*it*M - 0.5*it^2*acc; O1=y; O2 = 1.5*I - 0.5*y   (Y1,Z1)
// MODE 4: O1 = acc (P=Y1^2); O2 = 2.25*I - 1.5*M + 0.25*acc (W=Z1^2)
// MODE 1: O1 = 1.5*M - 0.5*acc   (Y2 and Z2)
// MODE 0: O1 = acc               (R=Y2^2)
// MODE 3: out_triu = sqrt(tr) * (1.5*M - 0.5*acc)
template<int MODE>
__global__ __launch_bounds__(256, 2)
void ns_mfma(const ushort_t* __restrict__ Ah, const ushort_t* __restrict__ Al,
             const ushort_t* __restrict__ Bh, const ushort_t* __restrict__ Bl,
             const ushort_t* __restrict__ Mh, const ushort_t* __restrict__ Ml,
             const float* __restrict__ tr,
             ushort_t* __restrict__ O1h, ushort_t* __restrict__ O1l,
             ushort_t* __restrict__ O2h, ushort_t* __restrict__ O2l,
             float* __restrict__ outT) {
    int tile, bb;
    decode_bid(blockIdx.x, tile, bb);
    const int rowBase = (tile >> 2) * 128, colBase = (tile & 3) * 64;
    if (MODE == 3 && colBase + 64 <= rowBase) return;
    __shared__ __align__(16) float fsmem[18624];   // 74.5 KB: 3 staging bufs / bounce overlay
    ushort_t* us = (ushort_t*)fsmem;
    const size_t mb = (size_t)bb * MSZ;
    const int tid = threadIdx.x, lane = tid & 63, wv = tid >> 6;
    const int khalf = lane >> 5, lrow = lane & 31;
    const int bhalf = (colBase >> 6) & 1;
    const ushort_t* arrp[4] = {
        Ah + mb + (size_t)(rowBase >> 7) * 32768,
        Al + mb + (size_t)(rowBase >> 7) * 32768,
        Bh + mb + (size_t)(colBase >> 7) * 32768,
        Bl + mb + (size_t)(colBase >> 7) * 32768 };

    floatx16 acc[2];
    #pragma unroll
    for (int cq = 0; cq < 2; ++cq)
        #pragma unroll
        for (int i = 0; i < 16; ++i) acc[cq][i] = 0.f;

    // prologue: 2 stages in flight (12 loads/wave outstanding)
    ns_prefetch(arrp, bhalf, us, wv, lane, 0, 0);
    ns_prefetch(arrp, bhalf, us, wv, lane, 1, STG);
    #pragma unroll
    for (int s = 0; s < 8; ++s) {
        if (s < 7) asm volatile("s_waitcnt vmcnt(6)" ::: "memory");
        else       asm volatile("s_waitcnt vmcnt(0)" ::: "memory");
        rawbar();
        // issue s+2 into the buffer freed at stage s-1 (reads retired before
        // each wave's last stage-(s-1) MFMA, so post-barrier DMA is safe)
        if (s < 6) ns_prefetch(arrp, bhalf, us, wv, lane, s + 2, ((s + 2) % 3) * STG);
        mfma_stage4(us, (s % 3) * STG, wv, khalf, lrow, acc);
    }

    acc_bounce(fsmem, acc, wv, khalf, lrow);
    const int rloc = tid & 127;
    const int r = rowBase + rloc;
    float it = 0.f, st = 0.f;
    if (MODE == 2) it = 1.0f / tr[bb];
    if (MODE == 3) st = sqrtf(tr[bb]);
    #pragma unroll
    for (int gi = 0; gi < 4; ++gi) {
        int g = (tid >> 7) + gi * 2;
        int c0 = colBase + g * 8;
        int so = swoff(r, c0);
        float v[8];
        #pragma unroll
        for (int j = 0; j < 8; ++j) v[j] = fsmem[rloc * 65 + g * 8 + j];
        if (MODE == 0) {
            store8(O1h + mb + so, O1l + mb + so, v);
        } else {
            float mv[8];
            {
                uint4 mh4 = *(const uint4*)(Mh + mb + so);
                uint4 ml4 = *(const uint4*)(Ml + mb + so);
                const uint_t mhw[4] = {mh4.x, mh4.y, mh4.z, mh4.w};
                const uint_t mlw[4] = {ml4.x, ml4.y, ml4.z, ml4.w};
                #pragma unroll
                for (int i = 0; i < 4; ++i) {
                    mv[2*i]   = __uint_as_float(mhw[i] << 16) + __uint_as_float(mlw[i] << 16);
                    mv[2*i+1] = __uint_as_float(mhw[i] & 0xffff0000u) + __uint_as_float(mlw[i] & 0xffff0000u);
                }
            }
            if (MODE == 1) {
                float y[8];
                #pragma unroll
                for (int j = 0; j < 8; ++j) y[j] = fmaf(1.5f, mv[j], -0.5f * v[j]);
                store8(O1h + mb + so, O1l + mb + so, y);
            } else if (MODE == 2) {
                float y[8], z[8];
                #pragma unroll
                for (int j = 0; j < 8; ++j) {
                    y[j] = 1.5f * it * mv[j] - 0.5f * it * it * v[j];
                    z[j] = ((r == c0 + j) ? 1.5f : 0.f) - 0.5f * y[j];
                }
                store8(O1h + mb + so, O1l + mb + so, y);
                store8(O2h + mb + so, O2l + mb + so, z);
            } else if (MODE == 4) {
                float w[8];
                #pragma unroll
                for (int j = 0; j < 8; ++j)
                    w[j] = ((r == c0 + j) ? 2.25f : 0.f) - 1.5f * mv[j] + 0.25f * v[j];
                store8(O1h + mb + so, O1l + mb + so, v);   // P = acc
                store8(O2h + mb + so, O2l + mb + so, w);   // W = Z1^2
            } else {   // MODE 3
                int tb = r * CD - (r * (r - 1)) / 2 - r;
                #pragma unroll
                for (int j = 0; j < 8; ++j) {
                    float y = fmaf(1.5f, mv[j], -0.5f * v[j]);
                    int c = c0 + j;
                    if (c >= r) outT[(size_t)bb * TRIU_N + tb + c] = st * y;
                }
            }
        }
    }
}

// ---------------------------------------------------------------------------
// Chain (all matrices commute; iterates exactly symmetric -> NT GEMMs):
//   G1: Y1 = 1.5*it*S - 0.5*it^2*S^2 ; Z1 = 1.5I - 0.5*Y1        [mode2]
//   G2: P = Y1^2 ; W = Z1^2 = 2.25I - 1.5*Y1 + 0.25*P (free)     [mode4]
//   G3: Y2 = 1.5*Y1 - 0.5*Z1*P                                    [mode1]
//   G4: Z2 = 1.5*Z1 - 0.5*W*Y2                                    [mode1]
//   G5: R = Y2^2                                                  [mode0]
//   G6: out = sqrt(tr) * (1.5*Y2 - 0.5*Z2*R), triu-packed         [mode3]
extern "C" void kernel_launch(void* const* d_in, const int* in_sizes, int n_in,
                              void* d_out, int out_size, void* d_ws, size_t ws_size,
                              hipStream_t stream) {
    const float* x = (const float*)d_in[0];
    float* out = (float*)d_out;
    char* ws = (char*)d_ws;
    const size_t HS = (size_t)BATCH * MSZ * 2;   // bytes per matrix array (8 MB)
    ushort_t* S0h = (ushort_t*)(ws + 0 * HS);
    ushort_t* S0l = (ushort_t*)(ws + 1 * HS);
    ushort_t* S1h = (ushort_t*)(ws + 2 * HS);
    ushort_t* S1l = (ushort_t*)(ws + 3 * HS);
    ushort_t* S2h = (ushort_t*)(ws + 4 * HS);
    ushort_t* S2l = (ushort_t*)(ws + 5 * HS);
    ushort_t* S3h = (ushort_t*)(ws + 6 * HS);
    ushort_t* S3l = (ushort_t*)(ws + 7 * HS);
    ushort_t* S4h = (ushort_t*)(ws + 8 * HS);
    ushort_t* S4l = (ushort_t*)(ws + 9 * HS);
    float* means = (float*)(ws + 10 * HS);
    float* tr = means + BATCH * CD;

    hipMemsetAsync(tr, 0, BATCH * sizeof(float), stream);
    // Sigma -> S0 (means + trace fused)
    gram_mfma<<<512, 256, 0, stream>>>(x, means, tr, S0h, S0l);
    // G1: Y1 -> S1, Z1 -> S2
    ns_mfma<2><<<512, 256, 0, stream>>>(S0h, S0l, S0h, S0l, S0h, S0l, tr,
                                        S1h, S1l, S2h, S2l, nullptr);
    // G2: P -> S3, W -> S0 (Sigma dead)
    ns_mfma<4><<<512, 256, 0, stream>>>(S1h, S1l, S1h, S1l, S1h, S1l, tr,
                                        S3h, S3l, S0h, S0l, nullptr);
    // G3: Y2 = 1.5*Y1 - 0.5*Z1*P -> S4
    ns_mfma<1><<<512, 256, 0, stream>>>(S2h, S2l, S3h, S3l, S1h, S1l, tr,
                                        S4h, S4l, nullptr, nullptr, nullptr);
    // G4: Z2 = 1.5*Z1 - 0.5*W*Y2 -> S1 (Y1 dead)
    ns_mfma<1><<<512, 256, 0, stream>>>(S0h, S0l, S4h, S4l, S2h, S2l, tr,
                                        S1h, S1l, nullptr, nullptr, nullptr);
    // G5: R = Y2^2 -> S3 (P dead)
    ns_mfma<0><<<512, 256, 0, stream>>>(S4h, S4l, S4h, S4l, nullptr, nullptr, tr,
                                        S3h, S3l, nullptr, nullptr, nullptr);
    // G6: out = sqrt(tr) * (1.5*Y2 - 0.5*Z2*R), triu-packed
    ns_mfma<3><<<512, 256, 0, stream>>>(S1h, S1l, S3h, S3l, S4h, S4l, tr,
                                        nullptr, nullptr, nullptr, nullptr, out);
}

// Round 7
// 200.602 us; speedup vs baseline: 1.0948x; 1.0948x over previous
//
#include <hip/hip_runtime.h>
#include <math.h>

#define BATCH 64
#define CD 256
#define NX 784
#define TRIU_N 32896
#define MSZ 65536           // elems per swizzled 256x256 matrix
#define REG_STRIDE 1032     // 128 rows * 8 elems + 8 pad (bank-conflict break)
#define ARR_STRIDE 4128     // 4 regions
#define BUF_STRIDE 16512    // 4 arrays (Ahi,Alo,Bhi,Blo) = 33KB per stage buffer

typedef unsigned short ushort_t;
typedef unsigned int uint_t;
typedef __attribute__((ext_vector_type(8))) short short8;
typedef __attribute__((ext_vector_type(16))) float floatx16;

// XCD co-location (round-5 proven): all 4 tiles of a batch on one XCD.
__device__ __forceinline__ void decode_bid(int bid, int& tile, int& bb) {
    int xcd = bid & 7, g = bid >> 3;
    tile = g & 3;
    bb = ((g >> 2) << 3) | xcd;
}

__device__ __forceinline__ float bf2f(ushort_t h) {
    return __uint_as_float(((uint_t)h) << 16);
}
__device__ __forceinline__ void pack2(float f0, float f1, uint_t& hp, uint_t& lp) {
    uint_t h, l;
    asm("v_cvt_pk_bf16_f32 %0, %1, %2" : "=v"(h) : "v"(f0), "v"(f1));
    float r0 = f0 - __uint_as_float(h << 16);
    float r1 = f1 - __uint_as_float(h & 0xffff0000u);
    asm("v_cvt_pk_bf16_f32 %0, %1, %2" : "=v"(l) : "v"(r0), "v"(r1));
    hp = h; lp = l;
}
__device__ __forceinline__ void store8(ushort_t* H, ushort_t* L, const float* y) {
    uint_t hw[4], lw[4];
    #pragma unroll
    for (int i = 0; i < 4; ++i) pack2(y[2*i], y[2*i+1], hw[i], lw[i]);
    *(uint4*)H = make_uint4(hw[0], hw[1], hw[2], hw[3]);
    *(uint4*)L = make_uint4(lw[0], lw[1], lw[2], lw[3]);
}

// swizzled offset of element (r,c) within one 256x256 matrix
__device__ __forceinline__ int swoff(int r, int c) {
    int p = r >> 7, s = (c >> 5) & 7, ks = (c >> 4) & 1, kh = (c >> 3) & 1;
    return ((((p * 8 + s) * 2 + ks) * 2 + kh) * 128 + (r & 127)) * 8 + (c & 7);
}

// raw workgroup barrier (no compiler vmcnt(0) drain); caller must wait first.
__device__ __forceinline__ void rawbar() {
    __builtin_amdgcn_s_barrier();
    __builtin_amdgcn_sched_barrier(0);
}

// ---------------------------------------------------------------------------
// One BK=32 stage from LDS: wave computes 2 quadrants (wr, wcp*2+{0,1}).
__device__ __forceinline__ void mfma_stage8(const ushort_t* us, int bufbase,
                                            int wr, int wcp, int khalf, int lrow,
                                            floatx16* acc) {
    __builtin_amdgcn_s_setprio(1);
    #pragma unroll
    for (int ks = 0; ks < 2; ++ks) {
        const int rid = ks * 2 + khalf;
        const ushort_t* rb = us + bufbase + rid * REG_STRIDE + lrow * 8;
        short8 aH = *(const short8*)(rb + wr * 256);
        short8 aL = *(const short8*)(rb + ARR_STRIDE + wr * 256);
        #pragma unroll
        for (int cq = 0; cq < 2; ++cq) {
            const int col = wcp * 2 + cq;
            short8 bH = *(const short8*)(rb + 2 * ARR_STRIDE + col * 256);
            short8 bL = *(const short8*)(rb + 3 * ARR_STRIDE + col * 256);
            acc[cq] = __builtin_amdgcn_mfma_f32_32x32x16_bf16(aH, bH, acc[cq], 0, 0, 0);
            acc[cq] = __builtin_amdgcn_mfma_f32_32x32x16_bf16(aH, bL, acc[cq], 0, 0, 0);
            acc[cq] = __builtin_amdgcn_mfma_f32_32x32x16_bf16(aL, bH, acc[cq], 0, 0, 0);
        }
    }
    __builtin_amdgcn_s_setprio(0);
}

// accumulator -> fsmem bounce (stride 129 -> conflict-free)
__device__ __forceinline__ void acc_bounce(float* fsmem, const floatx16* acc,
                                           int wr, int wcp, int khalf, int lrow) {
    __syncthreads();
    #pragma unroll
    for (int cq = 0; cq < 2; ++cq)
        #pragma unroll
        for (int i = 0; i < 16; ++i) {
            int rl = (i & 3) + ((i >> 2) << 3) + (khalf << 2);
            fsmem[(wr * 32 + rl) * 129 + (wcp * 2 + cq) * 32 + lrow] = acc[cq][i];
        }
    __syncthreads();
}

// ---------------------------------------------------------------------------
// Gram helpers: named-register double buffer (static indexing, rule #20)
struct Cur { float4 v[2][2]; };

__device__ __forceinline__ void gr_load(const float* Xb, int rowBase, int colBase, int s,
                                        const int* side, const int* srow, const int* skq,
                                        Cur& c) {
    #pragma unroll
    for (int q = 0; q < 2; ++q) {
        int gk = s * 32 + skq[q] * 8;
        if (gk < NX) {
            const float* p = Xb + (size_t)((side[q] ? colBase : rowBase) + srow[q]) * NX + gk;
            c.v[q][0] = *(const float4*)p;
            c.v[q][1] = *(const float4*)(p + 4);
        } else {
            c.v[q][0] = make_float4(0.f, 0.f, 0.f, 0.f);
            c.v[q][1] = make_float4(0.f, 0.f, 0.f, 0.f);
        }
    }
}

__device__ __forceinline__ void gr_conv(ushort_t* us, int bufbase, const Cur& c,
                                        const int* side, const int* srow, const int* skq,
                                        float* rs) {
    #pragma unroll
    for (int q = 0; q < 2; ++q) {
        float f[8] = {c.v[q][0].x, c.v[q][0].y, c.v[q][0].z, c.v[q][0].w,
                      c.v[q][1].x, c.v[q][1].y, c.v[q][1].z, c.v[q][1].w};
        rs[q] += ((f[0] + f[1]) + (f[2] + f[3])) + ((f[4] + f[5]) + (f[6] + f[7]));
        uint_t hp[4], lp[4];
        #pragma unroll
        for (int i = 0; i < 4; ++i) pack2(f[2*i], f[2*i+1], hp[i], lp[i]);
        int base = bufbase + (side[q] * 2) * ARR_STRIDE + skq[q] * REG_STRIDE + srow[q] * 8;
        *(uint4*)(us + base)              = make_uint4(hp[0], hp[1], hp[2], hp[3]);
        *(uint4*)(us + base + ARR_STRIDE) = make_uint4(lp[0], lp[1], lp[2], lp[3]);
    }
}

// ---------------------------------------------------------------------------
// Gram: Sigma = X X^T / n - m m^T. Means + trace fused. 2-stage-ahead load
// pipeline, raw barriers with lgkmcnt(0) only. (round-5 proven, 45.6 us)
__global__ __launch_bounds__(512, 1)
void gram_mfma(const float* __restrict__ X, float* __restrict__ means,
               float* __restrict__ tr,
               ushort_t* __restrict__ Gh, ushort_t* __restrict__ Gl) {
    __shared__ __align__(16) float fsmem[16512];   // 66 KB: 2 staging bufs OR epilogue tile
    __shared__ float dsh[8];
    ushort_t* us = (ushort_t*)fsmem;
    int tile, bb;
    decode_bid(blockIdx.x, tile, bb);
    const int rowBase = (tile >> 1) * 128, colBase = (tile & 1) * 128;
    const int tid = threadIdx.x, lane = tid & 63, wv = tid >> 6;
    const int wr = wv >> 1, wcp = wv & 1;
    const int khalf = lane >> 5, lrow = lane & 31;
    const float* Xb = X + (size_t)bb * CD * NX;

    floatx16 acc[2];
    #pragma unroll
    for (int cq = 0; cq < 2; ++cq)
        #pragma unroll
        for (int i = 0; i < 16; ++i) acc[cq][i] = 0.f;

    int side[2], srow[2], skq[2];
    #pragma unroll
    for (int q = 0; q < 2; ++q) {
        int gid = q * 512 + tid;
        side[q] = gid >> 9;
        srow[q] = (gid >> 2) & 127;
        skq[q]  = gid & 3;
    }
    float rs[2] = {0.f, 0.f};

    Cur curA, curB;
    gr_load(Xb, rowBase, colBase, 0, side, srow, skq, curA);
    gr_load(Xb, rowBase, colBase, 1, side, srow, skq, curB);
    gr_conv(us, 0, curA, side, srow, skq, rs);          // stage 0 -> buf0

    for (int s = 0; s < 25; s += 2) {
        // ---- even stage s (reads buf0) ----
        asm volatile("s_waitcnt lgkmcnt(0)" ::: "memory");
        rawbar();
        if (s + 2 <= 24) gr_load(Xb, rowBase, colBase, s + 2, side, srow, skq, curA);
        mfma_stage8(us, 0, wr, wcp, khalf, lrow, acc);
        if (s + 1 <= 24) gr_conv(us, BUF_STRIDE, curB, side, srow, skq, rs);
        // ---- odd stage s+1 (reads buf1) ----
        if (s + 1 <= 24) {
            asm volatile("s_waitcnt lgkmcnt(0)" ::: "memory");
            rawbar();
            if (s + 3 <= 24) gr_load(Xb, rowBase, colBase, s + 3, side, srow, skq, curB);
            mfma_stage8(us, BUF_STRIDE, wr, wcp, khalf, lrow, acc);
            gr_conv(us, 0, curA, side, srow, skq, rs);
        }
    }

    // means: reduce the 4 lanes (skq 0..3) sharing a row; write both panels.
    {
        float r0 = rs[0], r1 = rs[1];
        r0 += __shfl_xor(r0, 1, 64); r0 += __shfl_xor(r0, 2, 64);
        r1 += __shfl_xor(r1, 1, 64); r1 += __shfl_xor(r1, 2, 64);
        if ((tid & 3) == 0) {
            int rr = tid >> 2;
            means[bb * CD + rowBase + rr] = r0 * (1.0f / NX);
            means[bb * CD + colBase + rr] = r1 * (1.0f / NX);
        }
    }

    acc_bounce(fsmem, acc, wr, wcp, khalf, lrow);   // full-drain syncthreads flushes means stores
    const int rloc = tid & 127;
    const int r = rowBase + rloc;
    const float mr = means[bb * CD + r];
    const bool diagblk = (rowBase == colBase);
    float dv = 0.f;
    #pragma unroll
    for (int gi = 0; gi < 4; ++gi) {
        int g = (tid >> 7) + gi * 4;
        int c0 = colBase + g * 8;
        int so = swoff(r, c0);
        float v[8];
        #pragma unroll
        for (int j = 0; j < 8; ++j) {
            v[j] = fsmem[rloc * 129 + g * 8 + j] * (1.0f / NX) - mr * means[bb * CD + c0 + j];
            if (diagblk && (c0 + j) == r) dv += v[j];
        }
        store8(Gh + (size_t)bb * MSZ + so, Gl + (size_t)bb * MSZ + so, v);
    }
    if (diagblk) {
        for (int off = 32; off; off >>= 1) dv += __shfl_down(dv, off, 64);
        if (lane == 0) dsh[wv] = dv;
        __syncthreads();
        if (tid == 0) {
            float s = ((dsh[0] + dsh[1]) + (dsh[2] + dsh[3]))
                    + ((dsh[4] + dsh[5]) + (dsh[6] + dsh[7]));
            atomicAdd(&tr[bb], s);
        }
    }
}

// ---------------------------------------------------------------------------
__device__ __forceinline__ void ns_prefetch(const ushort_t* const* arrp, ushort_t* us,
                                            int wv, int lane, int s, int buf) {
    #pragma unroll
    for (int j = 0; j < 4; ++j) {
        int ck = wv * 4 + j;
        int arr = ck >> 3, rid = (ck >> 1) & 3, half = ck & 1;
        const ushort_t* g = arrp[arr] + s * 4096 + rid * 1024 + half * 512 + lane * 8;
        ushort_t* l = us + buf * BUF_STRIDE + arr * ARR_STRIDE + rid * REG_STRIDE + half * 512;
        __builtin_amdgcn_global_load_lds(
            (const __attribute__((address_space(1))) unsigned int*)g,
            (__attribute__((address_space(3))) unsigned int*)l, 16, 0, 0);
    }
}

// NS GEMM (round-5 proven): 4-buf pipeline, counted vmcnt.
// MODE 2: y = 1.5*it*M - 0.5*it^2*acc; O1=y; O2 = 1.5*I - 0.5*y   (Y1,Z1)
// MODE 4: O1 = acc (P=Y1^2); O2 = 2.25*I - 1.5*M + 0.25*acc (W=Z1^2)
// MODE 1: O1 = 1.5*M - 0.5*acc   (Y2)
// MODE 3: out_triu = sqrt(tr) * (1.5*M - 0.5*acc)
template<int MODE>
__global__ __launch_bounds__(512, 1)
void ns_mfma(const ushort_t* __restrict__ Ah, const ushort_t* __restrict__ Al,
             const ushort_t* __restrict__ Bh, const ushort_t* __restrict__ Bl,
             const ushort_t* __restrict__ Mh, const ushort_t* __restrict__ Ml,
             const float* __restrict__ tr,
             ushort_t* __restrict__ O1h, ushort_t* __restrict__ O1l,
             ushort_t* __restrict__ O2h, ushort_t* __restrict__ O2l,
             float* __restrict__ outT) {
    int tile, bb;
    decode_bid(blockIdx.x, tile, bb);
    const int rowBase = (tile >> 1) * 128, colBase = (tile & 1) * 128;
    if (MODE == 3 && rowBase > colBase) return;
    __shared__ __align__(16) float fsmem[33024];   // 132 KB: 4 staging bufs; epilogue overlays
    ushort_t* us = (ushort_t*)fsmem;
    const size_t mb = (size_t)bb * MSZ;
    const int tid = threadIdx.x, lane = tid & 63, wv = tid >> 6;
    const int wr = wv >> 1, wcp = wv & 1;
    const int khalf = lane >> 5, lrow = lane & 31;
    const ushort_t* arrp[4] = {
        Ah + mb + (size_t)(rowBase >> 7) * 32768,
        Al + mb + (size_t)(rowBase >> 7) * 32768,
        Bh + mb + (size_t)(colBase >> 7) * 32768,
        Bl + mb + (size_t)(colBase >> 7) * 32768 };

    floatx16 acc[2];
    #pragma unroll
    for (int cq = 0; cq < 2; ++cq)
        #pragma unroll
        for (int i = 0; i < 16; ++i) acc[cq][i] = 0.f;

    // prologue: 3 stages in flight (12 loads/wave outstanding)
    ns_prefetch(arrp, us, wv, lane, 0, 0);
    ns_prefetch(arrp, us, wv, lane, 1, 1);
    ns_prefetch(arrp, us, wv, lane, 2, 2);
    #pragma unroll
    for (int s = 0; s < 8; ++s) {
        if (s <= 5)      asm volatile("s_waitcnt vmcnt(8)" ::: "memory");
        else if (s == 6) asm volatile("s_waitcnt vmcnt(4)" ::: "memory");
        else             asm volatile("s_waitcnt vmcnt(0)" ::: "memory");
        rawbar();
        mfma_stage8(us, (s & 3) * BUF_STRIDE, wr, wcp, khalf, lrow, acc);
        if (s < 5) ns_prefetch(arrp, us, wv, lane, s + 3, (s + 3) & 3);
    }

    acc_bounce(fsmem, acc, wr, wcp, khalf, lrow);
    const int rloc = tid & 127;
    const int r = rowBase + rloc;
    float it = 0.f, st = 0.f;
    if (MODE == 2) it = 1.0f / tr[bb];
    if (MODE == 3) st = sqrtf(tr[bb]);
    #pragma unroll
    for (int gi = 0; gi < 4; ++gi) {
        int g = (tid >> 7) + gi * 4;
        int c0 = colBase + g * 8;
        int so = swoff(r, c0);
        float v[8];
        #pragma unroll
        for (int j = 0; j < 8; ++j) v[j] = fsmem[rloc * 129 + g * 8 + j];
        if (MODE == 0) {
            store8(O1h + mb + so, O1l + mb + so, v);
        } else {
            float mv[8];
            {
                uint4 mh4 = *(const uint4*)(Mh + mb + so);
                uint4 ml4 = *(const uint4*)(Ml + mb + so);
                const uint_t mhw[4] = {mh4.x, mh4.y, mh4.z, mh4.w};
                const uint_t mlw[4] = {ml4.x, ml4.y, ml4.z, ml4.w};
                #pragma unroll
                for (int i = 0; i < 4; ++i) {
                    mv[2*i]   = __uint_as_float(mhw[i] << 16) + __uint_as_float(mlw[i] << 16);
                    mv[2*i+1] = __uint_as_float(mhw[i] & 0xffff0000u) + __uint_as_float(mlw[i] & 0xffff0000u);
                }
            }
            if (MODE == 1) {
                float y[8];
                #pragma unroll
                for (int j = 0; j < 8; ++j) y[j] = fmaf(1.5f, mv[j], -0.5f * v[j]);
                store8(O1h + mb + so, O1l + mb + so, y);
            } else if (MODE == 2) {
                float y[8], z[8];
                #pragma unroll
                for (int j = 0; j < 8; ++j) {
                    y[j] = 1.5f * it * mv[j] - 0.5f * it * it * v[j];
                    z[j] = ((r == c0 + j) ? 1.5f : 0.f) - 0.5f * y[j];
                }
                store8(O1h + mb + so, O1l + mb + so, y);
                store8(O2h + mb + so, O2l + mb + so, z);
            } else if (MODE == 4) {
                float w[8];
                #pragma unroll
                for (int j = 0; j < 8; ++j)
                    w[j] = ((r == c0 + j) ? 2.25f : 0.f) - 1.5f * mv[j] + 0.25f * v[j];
                store8(O1h + mb + so, O1l + mb + so, v);   // P = acc
                store8(O2h + mb + so, O2l + mb + so, w);   // W = Z1^2
            } else {   // MODE 3
                int tb = r * CD - (r * (r - 1)) / 2 - r;
                #pragma unroll
                for (int j = 0; j < 8; ++j) {
                    float y = fmaf(1.5f, mv[j], -0.5f * v[j]);
                    int c = c0 + j;
                    if (c >= r) outT[(size_t)bb * TRIU_N + tb + c] = st * y;
                }
            }
        }
    }
}

// ---------------------------------------------------------------------------
// Paired dispatch: G4 (Z2 = 1.5*Z1 - 0.5*W*Y2) and G5 (R = Y2^2) are
// independent given Y2 -> run both in ONE dispatch, 512 blocks, 2 blocks/CU
// (one G4 + one G5 per CU, different GEMMs -> no staging duplication).
// 66 KB LDS (2-buf, issue-after-barrier, prefetch distance 1 stage).
__global__ __launch_bounds__(512, 4)
void ns_pair(const ushort_t* __restrict__ Wh, const ushort_t* __restrict__ Wl,
             const ushort_t* __restrict__ Y2h, const ushort_t* __restrict__ Y2l,
             const ushort_t* __restrict__ Z1h, const ushort_t* __restrict__ Z1l,
             ushort_t* __restrict__ Z2h, ushort_t* __restrict__ Z2l,
             ushort_t* __restrict__ Rh, ushort_t* __restrict__ Rl) {
    const int gid = blockIdx.x;
    const int xcd = gid & 7, g = gid >> 3;
    const int which = g & 1, t2 = g >> 1;          // which: 0 = G4, 1 = G5
    const int tile = t2 & 3, bb = ((t2 >> 2) << 3) | xcd;
    const int rowBase = (tile >> 1) * 128, colBase = (tile & 1) * 128;
    __shared__ __align__(16) float fsmem[16512];   // 66 KB: 2 staging bufs / bounce overlay
    ushort_t* us = (ushort_t*)fsmem;
    const size_t mb = (size_t)bb * MSZ;
    const int tid = threadIdx.x, lane = tid & 63, wv = tid >> 6;
    const int wr = wv >> 1, wcp = wv & 1;
    const int khalf = lane >> 5, lrow = lane & 31;
    const ushort_t* Ah = which ? Y2h : Wh;
    const ushort_t* Al = which ? Y2l : Wl;
    const ushort_t* arrp[4] = {
        Ah  + mb + (size_t)(rowBase >> 7) * 32768,
        Al  + mb + (size_t)(rowBase >> 7) * 32768,
        Y2h + mb + (size_t)(colBase >> 7) * 32768,
        Y2l + mb + (size_t)(colBase >> 7) * 32768 };

    floatx16 acc[2];
    #pragma unroll
    for (int cq = 0; cq < 2; ++cq)
        #pragma unroll
        for (int i = 0; i < 16; ++i) acc[cq][i] = 0.f;

    // 2-buf schedule: L(s+1) issued after the barrier of stage s (the target
    // buffer was read at stage s-1; the barrier proves all waves are done).
    ns_prefetch(arrp, us, wv, lane, 0, 0);
    ns_prefetch(arrp, us, wv, lane, 1, 1);
    #pragma unroll
    for (int s = 0; s < 8; ++s) {
        if (s == 0) asm volatile("s_waitcnt vmcnt(4)" ::: "memory");
        else        asm volatile("s_waitcnt vmcnt(0)" ::: "memory");
        rawbar();
        if (s >= 1 && s < 7) ns_prefetch(arrp, us, wv, lane, s + 1, (s + 1) & 1);
        mfma_stage8(us, (s & 1) * BUF_STRIDE, wr, wcp, khalf, lrow, acc);
    }

    acc_bounce(fsmem, acc, wr, wcp, khalf, lrow);
    const int rloc = tid & 127;
    const int r = rowBase + rloc;
    #pragma unroll
    for (int gi = 0; gi < 4; ++gi) {
        int gq = (tid >> 7) + gi * 4;
        int c0 = colBase + gq * 8;
        int so = swoff(r, c0);
        float v[8];
        #pragma unroll
        for (int j = 0; j < 8; ++j) v[j] = fsmem[rloc * 129 + gq * 8 + j];
        if (which) {                                  // G5: R = Y2^2
            store8(Rh + mb + so, Rl + mb + so, v);
        } else {                                      // G4: Z2 = 1.5*Z1 - 0.5*W*Y2
            uint4 mh4 = *(const uint4*)(Z1h + mb + so);
            uint4 ml4 = *(const uint4*)(Z1l + mb + so);
            const uint_t mhw[4] = {mh4.x, mh4.y, mh4.z, mh4.w};
            const uint_t mlw[4] = {ml4.x, ml4.y, ml4.z, ml4.w};
            float y[8];
            #pragma unroll
            for (int i = 0; i < 4; ++i) {
                float m0 = __uint_as_float(mhw[i] << 16) + __uint_as_float(mlw[i] << 16);
                float m1 = __uint_as_float(mhw[i] & 0xffff0000u) + __uint_as_float(mlw[i] & 0xffff0000u);
                y[2*i]   = fmaf(1.5f, m0, -0.5f * v[2*i]);
                y[2*i+1] = fmaf(1.5f, m1, -0.5f * v[2*i+1]);
            }
            store8(Z2h + mb + so, Z2l + mb + so, y);
        }
    }
}

// ---------------------------------------------------------------------------
// Chain:
//   G1: Y1 = 1.5*it*S - 0.5*it^2*S^2 ; Z1 = 1.5I - 0.5*Y1        [mode2]
//   G2: P = Y1^2 ; W = Z1^2 = 2.25I - 1.5*Y1 + 0.25*P (free)     [mode4]
//   G3: Y2 = 1.5*Y1 - 0.5*Z1*P                                    [mode1]
//   G4||G5: Z2 = 1.5*Z1 - 0.5*W*Y2 ; R = Y2^2                     [ns_pair]
//   G6: out = sqrt(tr) * (1.5*Y2 - 0.5*Z2*R), triu-packed         [mode3]
extern "C" void kernel_launch(void* const* d_in, const int* in_sizes, int n_in,
                              void* d_out, int out_size, void* d_ws, size_t ws_size,
                              hipStream_t stream) {
    const float* x = (const float*)d_in[0];
    float* out = (float*)d_out;
    char* ws = (char*)d_ws;
    const size_t HS = (size_t)BATCH * MSZ * 2;   // bytes per matrix array (8 MB)
    ushort_t* S0h = (ushort_t*)(ws + 0 * HS);
    ushort_t* S0l = (ushort_t*)(ws + 1 * HS);
    ushort_t* S1h = (ushort_t*)(ws + 2 * HS);
    ushort_t* S1l = (ushort_t*)(ws + 3 * HS);
    ushort_t* S2h = (ushort_t*)(ws + 4 * HS);
    ushort_t* S2l = (ushort_t*)(ws + 5 * HS);
    ushort_t* S3h = (ushort_t*)(ws + 6 * HS);
    ushort_t* S3l = (ushort_t*)(ws + 7 * HS);
    ushort_t* S4h = (ushort_t*)(ws + 8 * HS);
    ushort_t* S4l = (ushort_t*)(ws + 9 * HS);
    float* means = (float*)(ws + 10 * HS);
    float* tr = means + BATCH * CD;

    hipMemsetAsync(tr, 0, BATCH * sizeof(float), stream);
    // Sigma -> S0 (means + trace fused)
    gram_mfma<<<256, 512, 0, stream>>>(x, means, tr, S0h, S0l);
    // G1: Y1 -> S1, Z1 -> S2
    ns_mfma<2><<<256, 512, 0, stream>>>(S0h, S0l, S0h, S0l, S0h, S0l, tr,
                                        S1h, S1l, S2h, S2l, nullptr);
    // G2: P -> S3, W -> S0 (Sigma dead)
    ns_mfma<4><<<256, 512, 0, stream>>>(S1h, S1l, S1h, S1l, S1h, S1l, tr,
                                        S3h, S3l, S0h, S0l, nullptr);
    // G3: Y2 = 1.5*Y1 - 0.5*Z1*P -> S4
    ns_mfma<1><<<256, 512, 0, stream>>>(S2h, S2l, S3h, S3l, S1h, S1l, tr,
                                        S4h, S4l, nullptr, nullptr, nullptr);
    // G4||G5: Z2 -> S1 (Y1 dead), R -> S3 (P dead)
    ns_pair<<<512, 512, 0, stream>>>(S0h, S0l, S4h, S4l, S2h, S2l,
                                     S1h, S1l, S3h, S3l);
    // G6: out = sqrt(tr) * (1.5*Y2 - 0.5*Z2*R), triu-packed
    ns_mfma<3><<<256, 512, 0, stream>>>(S1h, S1l, S3h, S3l, S4h, S4l, tr,
                                        nullptr, nullptr, nullptr, nullptr, out);
}